// Round 10
// baseline (328.358 us; speedup 1.0000x reference)
//
#include <hip/hip_runtime.h>

#define N_NODES 50000
#define N_EDGES 800000
#define D 128
#define NBKT 98       // ceil(50000/512) buckets of 512 dst nodes
#define BKT_SHIFT 9
#define BKT_CAP 16384 // padded per-bucket capacity (avg 8163, Poisson-safe)
#define EPB 8192      // edges per binning block (98 blocks)
#define NTILES 3125   // 50000 / 16 exactly

typedef __attribute__((ext_vector_type(8))) short bf16x8;
typedef __attribute__((ext_vector_type(4))) float f32x4;

__device__ __forceinline__ float bf2f(unsigned short u) {
  unsigned int v = ((unsigned int)u) << 16;
  return __uint_as_float(v);
}
__device__ __forceinline__ unsigned short f2bf(float f) {
  unsigned int u = __float_as_uint(f);
  unsigned int r = (u + 0x7fffu + ((u >> 16) & 1u)) >> 16;
  return (unsigned short)r;
}

// ---- merged fp32->bf16 casts: x (6250 blocks) + 5 weights (80 blocks) ---
__global__ __launch_bounds__(256) void k_castall(const float* __restrict__ x,
                                                 const float* __restrict__ w0,
                                                 const float* __restrict__ w1,
                                                 const float* __restrict__ w2,
                                                 const float* __restrict__ w3,
                                                 const float* __restrict__ w4,
                                                 unsigned short* __restrict__ xb,
                                                 unsigned short* __restrict__ wout) {
  int b = blockIdx.x;
  const float* src;
  unsigned short* dst;
  int i;
  if (b < 6250) {
    src = x; dst = xb; i = b * 256 + threadIdx.x;
  } else {
    int b2 = b - 6250;
    int m = b2 >> 4;
    i = (b2 & 15) * 256 + threadIdx.x;
    src = (m == 0) ? w0 : (m == 1) ? w1 : (m == 2) ? w2 : (m == 3) ? w3 : w4;
    dst = wout + m * 16384;
  }
  float4 v = ((const float4*)src)[i];
  ushort4 o;
  o.x = f2bf(v.x); o.y = f2bf(v.y); o.z = f2bf(v.z); o.w = f2bf(v.w);
  ((ushort4*)dst)[i] = o;
}

// ---- edge dtype probe + init of cursor (padded bases) and stats ---------
__global__ __launch_bounds__(256) void k_detect(const int* __restrict__ ei,
                                                int* __restrict__ flag,
                                                int* __restrict__ cursor,
                                                float* __restrict__ stats) {
  __shared__ int red[256];
  int t = threadIdx.x;
  if (t < NBKT) cursor[t] = t * BKT_CAP;
  stats[t] = 0.f;
  stats[t + 256] = 0.f;
  int acc = 0;
  for (int k = t; k < 8192; k += 256) acc |= ei[2 * k + 1];
  red[t] = acc;
  __syncthreads();
  for (int s = 128; s > 0; s >>= 1) {
    if (t < s) red[t] |= red[t + s];
    __syncthreads();
  }
  if (t == 0) flag[0] = (red[0] == 0) ? 1 : 0;  // 1 => int64
}

__device__ __forceinline__ int edge_at(const int* ei, int idx, int is64) {
  return is64 ? ei[2 * idx] : ei[idx];
}

// ---- one-pass binning into padded buckets -------------------------------
__global__ __launch_bounds__(256) void k_bin(const int* __restrict__ ei,
                                             const int* __restrict__ flag,
                                             int* __restrict__ cursor,
                                             unsigned int* __restrict__ binned) {
  __shared__ int h[128];
  __shared__ int resv[128];
  int t = threadIdx.x;
  if (t < 128) h[t] = 0;
  __syncthreads();
  int is64 = flag[0];
  int start = blockIdx.x * EPB;
  int end = min(start + EPB, N_EDGES);
  for (int e = start + t; e < end; e += 256) {
    int d = edge_at(ei, N_EDGES + e, is64);
    if ((unsigned)d < N_NODES) atomicAdd(&h[d >> BKT_SHIFT], 1);
  }
  __syncthreads();
  if (t < NBKT) {
    resv[t] = h[t] ? atomicAdd(&cursor[t], h[t]) : 0;
    h[t] = 0;
  }
  __syncthreads();
  for (int e = start + t; e < end; e += 256) {
    int d = edge_at(ei, N_EDGES + e, is64);
    int sv = edge_at(ei, e, is64);
    if ((unsigned)d < N_NODES && (unsigned)sv < N_NODES) {
      int b = d >> BKT_SHIFT;
      int r = atomicAdd(&h[b], 1);
      int pos = resv[b] + r;
      if (pos < (b + 1) * BKT_CAP) binned[pos] = (unsigned)sv | ((unsigned)d << 16);
    }
  }
}

// ---- per-bucket CSR: off (bucket-padded, stride 513) + srcs scatter -----
__global__ __launch_bounds__(256) void k_pass2(const int* __restrict__ cursor,
                                               const unsigned int* __restrict__ binned,
                                               int* __restrict__ off,
                                               unsigned short* __restrict__ srcs) {
  __shared__ int h[512];
  __shared__ int ps[256];
  __shared__ int sc[512];
  int t = threadIdx.x;
  int b = blockIdx.x;
  int base = b * BKT_CAP;
  int cnt = min(cursor[b] - base, BKT_CAP);
  h[t] = 0; h[t + 256] = 0;
  __syncthreads();
  for (int e = base + t; e < base + cnt; e += 256) {
    unsigned v = binned[e];
    int l = (int)(v >> 16) - (b << BKT_SHIFT);
    atomicAdd(&h[l], 1);
  }
  __syncthreads();
  int pair = h[2 * t] + h[2 * t + 1];
  ps[t] = pair;
  __syncthreads();
  for (int s = 1; s < 256; s <<= 1) {
    int add = (t >= s) ? ps[t - s] : 0;
    __syncthreads();
    ps[t] += add;
    __syncthreads();
  }
  int pexcl = ps[t] - pair;
  sc[2 * t] = pexcl;
  sc[2 * t + 1] = pexcl + h[2 * t];
  __syncthreads();
  h[t] = 0; h[t + 256] = 0;
  off[b * 513 + t] = base + sc[t];
  off[b * 513 + t + 256] = base + sc[t + 256];
  if (t == 0) off[b * 513 + 512] = base + cnt;
  __syncthreads();
  for (int e = base + t; e < base + cnt; e += 256) {
    unsigned v = binned[e];
    int l = (int)(v >> 16) - (b << BKT_SHIFT);
    int r = atomicAdd(&h[l], 1);
    srcs[base + sc[l] + r] = (unsigned short)(v & 0xffffu);
  }
}

// ---- mean aggregation, 2x-unrolled gather (8 rows in flight/wave) -------
template <bool NORM>
__device__ __forceinline__ void accum8(float* a, uint4 v, const float* sc,
                                       const float* bt) {
  const unsigned int* pv = (const unsigned int*)&v;
#pragma unroll
  for (int h = 0; h < 4; ++h) {
    float lo = bf2f((unsigned short)(pv[h] & 0xffffu));
    float hi = bf2f((unsigned short)(pv[h] >> 16));
    if (NORM) {
      a[2 * h] += fmaxf(fmaf(sc[2 * h], lo, bt[2 * h]), 0.f);
      a[2 * h + 1] += fmaxf(fmaf(sc[2 * h + 1], hi, bt[2 * h + 1]), 0.f);
    } else {
      a[2 * h] += lo;
      a[2 * h + 1] += hi;
    }
  }
}

template <bool NORM>
__global__ __launch_bounds__(256) void k_agg(const unsigned short* __restrict__ feat,
                                             const int* __restrict__ off,
                                             const unsigned short* __restrict__ srcs,
                                             const float* __restrict__ Sin,
                                             const float* __restrict__ gw,
                                             const float* __restrict__ gb,
                                             const float* __restrict__ ga,
                                             unsigned short* __restrict__ agg) {
  int wv = threadIdx.x >> 6;
  int lane = threadIdx.x & 63;
  int node = blockIdx.x * 4 + wv;
  if (node >= N_NODES) return;
  int q = lane >> 4, s = lane & 15;

  float sc[8], bt[8];
  if (NORM) {
    const float invN = 1.0f / (float)N_NODES;
#pragma unroll
    for (int i = 0; i < 8; ++i) {
      int f = s * 8 + i;
      float m = Sin[f] * invN;
      float ex2 = Sin[128 + f] * invN;
      float af = ga[f];
      float var = fmaxf(ex2 - (2.f * af - af * af) * m * m, 0.f);
      float rstd = rsqrtf(var + 1e-5f);
      sc[i] = gw[f] * rstd;
      bt[i] = gb[f] - sc[i] * af * m;
    }
  }

  int oidx = (node >> BKT_SHIFT) * 513 + (node & 511);
  int b = off[oidx], e = off[oidx + 1];
  const uint4* fp = (const uint4*)feat;
  float a[8] = {0.f, 0.f, 0.f, 0.f, 0.f, 0.f, 0.f, 0.f};
  for (int cb = b; cb < e; cb += 64) {
    int n = min(64, e - cb);
    int jv = (lane < n) ? (int)srcs[cb + lane] : 0;  // lanes>=n read j=0 (safe)
    int kmax = (n + 3) >> 2;
    int k = 0;
    for (; k + 2 <= kmax; k += 2) {
      int t0 = 4 * k + q;
      int t1 = t0 + 4;
      int j0 = __shfl(jv, t0);
      int j1 = __shfl(jv, t1);
      uint4 v0 = fp[j0 * 16 + s];
      uint4 v1 = fp[j1 * 16 + s];
      if (t0 < n) accum8<NORM>(a, v0, sc, bt);
      if (t1 < n) accum8<NORM>(a, v1, sc, bt);
    }
    if (k < kmax) {
      int t0 = 4 * k + q;
      int j0 = __shfl(jv, t0);
      uint4 v0 = fp[j0 * 16 + s];
      if (t0 < n) accum8<NORM>(a, v0, sc, bt);
    }
  }
#pragma unroll
  for (int i = 0; i < 8; ++i) {
    a[i] += __shfl_xor(a[i], 16);
    a[i] += __shfl_xor(a[i], 32);
  }
  if (q == 0) {
    float inv = 1.0f / (float)max(e - b, 1);
    uint4 o;
    o.x = (unsigned)f2bf(a[0] * inv) | ((unsigned)f2bf(a[1] * inv) << 16);
    o.y = (unsigned)f2bf(a[2] * inv) | ((unsigned)f2bf(a[3] * inv) << 16);
    o.z = (unsigned)f2bf(a[4] * inv) | ((unsigned)f2bf(a[5] * inv) << 16);
    o.w = (unsigned)f2bf(a[6] * inv) | ((unsigned)f2bf(a[7] * inv) << 16);
    ((uint4*)agg)[node * 16 + s] = o;
  }
}

// ---- conv GEMM: out = A@W1^T + B@W2^T + bias (bf16) + fused stats.
// 2-tile unrolled, weight-stationary; NORMB: B normalized via LDS params.
template <bool NORMB>
__global__ __launch_bounds__(256) void k_gemm_conv(const unsigned short* __restrict__ A,
                                                   const unsigned short* __restrict__ B,
                                                   const unsigned short* __restrict__ W1,
                                                   const unsigned short* __restrict__ W2,
                                                   const float* __restrict__ bias,
                                                   unsigned short* __restrict__ outv,
                                                   float* __restrict__ S,
                                                   const float* __restrict__ Sin,
                                                   const float* __restrict__ gw,
                                                   const float* __restrict__ gb,
                                                   const float* __restrict__ ga) {
  __shared__ float sred[2][128];
  __shared__ float nsc[128], nbt[128];
  const int tid = threadIdx.x;
  const int lane = tid & 63;
  const int wv = tid >> 6;
  const int quad = lane >> 4;
  const int l16 = lane & 15;
  const int colBase = wv * 32;

  if (NORMB) {
    if (tid < 128) {
      const float invN = 1.0f / (float)N_NODES;
      float m = Sin[tid] * invN;
      float ex2 = Sin[128 + tid] * invN;
      float af = ga[tid];
      float var = fmaxf(ex2 - (2.f * af - af * af) * m * m, 0.f);
      float rstd = rsqrtf(var + 1e-5f);
      float scv = gw[tid] * rstd;
      nsc[tid] = scv;
      nbt[tid] = gb[tid] - scv * af * m;
    }
    __syncthreads();
  }

  bf16x8 w1f[2][4], w2f[2][4];
  float bv[2];
#pragma unroll
  for (int c2 = 0; c2 < 2; ++c2) {
    int col = colBase + c2 * 16 + l16;
    bv[c2] = bias[col];
#pragma unroll
    for (int ks = 0; ks < 4; ++ks) {
      w1f[c2][ks] = *((const bf16x8*)&W1[col * 128 + ks * 32 + quad * 8]);
      w2f[c2][ks] = *((const bf16x8*)&W2[col * 128 + ks * 32 + quad * 8]);
    }
  }

  float p1[2] = {0.f, 0.f}, p2[2] = {0.f, 0.f};

  for (int t0 = 2 * blockIdx.x; t0 < NTILES - 1; t0 += 2 * gridDim.x) {
    bf16x8 af[2][4], bfr[2][4];
#pragma unroll
    for (int u = 0; u < 2; ++u) {
      int arow = (t0 + u) * 16 + l16;
#pragma unroll
      for (int ks = 0; ks < 4; ++ks) {
        af[u][ks] = *((const bf16x8*)&A[arow * 128 + ks * 32 + quad * 8]);
        bfr[u][ks] = *((const bf16x8*)&B[arow * 128 + ks * 32 + quad * 8]);
      }
    }
    if (NORMB) {
#pragma unroll
      for (int u = 0; u < 2; ++u)
#pragma unroll
        for (int ks = 0; ks < 4; ++ks) {
          int f0 = ks * 32 + quad * 8;
#pragma unroll
          for (int j = 0; j < 8; ++j) {
            float xv = bf2f((unsigned short)bfr[u][ks][j]);
            bfr[u][ks][j] = (short)f2bf(fmaxf(fmaf(nsc[f0 + j], xv, nbt[f0 + j]), 0.f));
          }
        }
    }
    f32x4 acc[2][2];
#pragma unroll
    for (int u = 0; u < 2; ++u)
#pragma unroll
      for (int c2 = 0; c2 < 2; ++c2) acc[u][c2] = (f32x4){0.f, 0.f, 0.f, 0.f};
#pragma unroll
    for (int u = 0; u < 2; ++u)
#pragma unroll
      for (int c2 = 0; c2 < 2; ++c2)
#pragma unroll
        for (int ks = 0; ks < 4; ++ks) {
          acc[u][c2] = __builtin_amdgcn_mfma_f32_16x16x32_bf16(af[u][ks], w1f[c2][ks], acc[u][c2], 0, 0, 0);
          acc[u][c2] = __builtin_amdgcn_mfma_f32_16x16x32_bf16(bfr[u][ks], w2f[c2][ks], acc[u][c2], 0, 0, 0);
        }
#pragma unroll
    for (int u = 0; u < 2; ++u)
#pragma unroll
      for (int c2 = 0; c2 < 2; ++c2) {
        int col = colBase + c2 * 16 + l16;
#pragma unroll
        for (int g = 0; g < 4; ++g) {
          int row = (t0 + u) * 16 + quad * 4 + g;
          float v = acc[u][c2][g] + bv[c2];
          outv[row * 128 + col] = f2bf(v);
          p1[c2] += v;
          p2[c2] += v * v;
        }
      }
  }

  if (blockIdx.x == gridDim.x - 1) {  // tail tile 3124
    const int tile = NTILES - 1;
    int arow = tile * 16 + l16;
    bf16x8 af[4], bfr[4];
#pragma unroll
    for (int ks = 0; ks < 4; ++ks) {
      af[ks] = *((const bf16x8*)&A[arow * 128 + ks * 32 + quad * 8]);
      bfr[ks] = *((const bf16x8*)&B[arow * 128 + ks * 32 + quad * 8]);
    }
    if (NORMB) {
#pragma unroll
      for (int ks = 0; ks < 4; ++ks) {
        int f0 = ks * 32 + quad * 8;
#pragma unroll
        for (int j = 0; j < 8; ++j) {
          float xv = bf2f((unsigned short)bfr[ks][j]);
          bfr[ks][j] = (short)f2bf(fmaxf(fmaf(nsc[f0 + j], xv, nbt[f0 + j]), 0.f));
        }
      }
    }
    f32x4 acc[2];
#pragma unroll
    for (int c2 = 0; c2 < 2; ++c2) acc[c2] = (f32x4){0.f, 0.f, 0.f, 0.f};
#pragma unroll
    for (int c2 = 0; c2 < 2; ++c2)
#pragma unroll
      for (int ks = 0; ks < 4; ++ks) {
        acc[c2] = __builtin_amdgcn_mfma_f32_16x16x32_bf16(af[ks], w1f[c2][ks], acc[c2], 0, 0, 0);
        acc[c2] = __builtin_amdgcn_mfma_f32_16x16x32_bf16(bfr[ks], w2f[c2][ks], acc[c2], 0, 0, 0);
      }
#pragma unroll
    for (int c2 = 0; c2 < 2; ++c2) {
      int col = colBase + c2 * 16 + l16;
#pragma unroll
      for (int g = 0; g < 4; ++g) {
        int row = tile * 16 + quad * 4 + g;
        float v = acc[c2][g] + bv[c2];
        outv[row * 128 + col] = f2bf(v);
        p1[c2] += v;
        p2[c2] += v * v;
      }
    }
  }

#pragma unroll
  for (int c2 = 0; c2 < 2; ++c2) {
    p1[c2] += __shfl_xor(p1[c2], 16); p1[c2] += __shfl_xor(p1[c2], 32);
    p2[c2] += __shfl_xor(p2[c2], 16); p2[c2] += __shfl_xor(p2[c2], 32);
  }
  if (quad == 0) {
#pragma unroll
    for (int c2 = 0; c2 < 2; ++c2) {
      sred[0][colBase + c2 * 16 + l16] = p1[c2];
      sred[1][colBase + c2 * 16 + l16] = p2[c2];
    }
  }
  __syncthreads();
  if (tid < 128) atomicAdd(&S[tid], sred[0][tid]);
  else atomicAdd(&S[tid], sred[1][tid - 128]);
}

// ---- residual GEMM: outres = B@Wres^T + bres (bf16). Low VGPR. ---------
__global__ __launch_bounds__(256) void k_gemm_res(const unsigned short* __restrict__ B,
                                                  const unsigned short* __restrict__ Wres,
                                                  const float* __restrict__ bres,
                                                  unsigned short* __restrict__ outres) {
  const int tid = threadIdx.x;
  const int lane = tid & 63;
  const int wv = tid >> 6;
  const int quad = lane >> 4;
  const int l16 = lane & 15;
  const int colBase = wv * 32;

  bf16x8 wrf[2][4];
  float bvR[2];
#pragma unroll
  for (int c2 = 0; c2 < 2; ++c2) {
    int col = colBase + c2 * 16 + l16;
    bvR[c2] = bres[col];
#pragma unroll
    for (int ks = 0; ks < 4; ++ks)
      wrf[c2][ks] = *((const bf16x8*)&Wres[col * 128 + ks * 32 + quad * 8]);
  }

  for (int t0 = 2 * blockIdx.x; t0 < NTILES - 1; t0 += 2 * gridDim.x) {
    bf16x8 bfr[2][4];
#pragma unroll
    for (int u = 0; u < 2; ++u) {
      int arow = (t0 + u) * 16 + l16;
#pragma unroll
      for (int ks = 0; ks < 4; ++ks)
        bfr[u][ks] = *((const bf16x8*)&B[arow * 128 + ks * 32 + quad * 8]);
    }
    f32x4 acc[2][2];
#pragma unroll
    for (int u = 0; u < 2; ++u)
#pragma unroll
      for (int c2 = 0; c2 < 2; ++c2) acc[u][c2] = (f32x4){0.f, 0.f, 0.f, 0.f};
#pragma unroll
    for (int u = 0; u < 2; ++u)
#pragma unroll
      for (int c2 = 0; c2 < 2; ++c2)
#pragma unroll
        for (int ks = 0; ks < 4; ++ks)
          acc[u][c2] = __builtin_amdgcn_mfma_f32_16x16x32_bf16(bfr[u][ks], wrf[c2][ks], acc[u][c2], 0, 0, 0);
#pragma unroll
    for (int u = 0; u < 2; ++u)
#pragma unroll
      for (int c2 = 0; c2 < 2; ++c2) {
        int col = colBase + c2 * 16 + l16;
#pragma unroll
        for (int g = 0; g < 4; ++g) {
          int row = (t0 + u) * 16 + quad * 4 + g;
          outres[row * 128 + col] = f2bf(acc[u][c2][g] + bvR[c2]);
        }
      }
  }

  if (blockIdx.x == gridDim.x - 1) {
    const int tile = NTILES - 1;
    int arow = tile * 16 + l16;
    bf16x8 bfr[4];
#pragma unroll
    for (int ks = 0; ks < 4; ++ks)
      bfr[ks] = *((const bf16x8*)&B[arow * 128 + ks * 32 + quad * 8]);
    f32x4 acc[2];
#pragma unroll
    for (int c2 = 0; c2 < 2; ++c2) acc[c2] = (f32x4){0.f, 0.f, 0.f, 0.f};
#pragma unroll
    for (int c2 = 0; c2 < 2; ++c2)
#pragma unroll
      for (int ks = 0; ks < 4; ++ks)
        acc[c2] = __builtin_amdgcn_mfma_f32_16x16x32_bf16(bfr[ks], wrf[c2][ks], acc[c2], 0, 0, 0);
#pragma unroll
    for (int c2 = 0; c2 < 2; ++c2) {
      int col = colBase + c2 * 16 + l16;
#pragma unroll
      for (int g = 0; g < 4; ++g) {
        int row = tile * 16 + quad * 4 + g;
        outres[row * 128 + col] = f2bf(acc[c2][g] + bvR[c2]);
      }
    }
  }
}

// ---- final GraphNorm + ReLU + bf16 residual -> fp32 d_out ---------------
__global__ __launch_bounds__(256) void k_norm2(const unsigned short* __restrict__ pre,
                                               const float* __restrict__ S,
                                               const float* __restrict__ w,
                                               const float* __restrict__ b,
                                               const float* __restrict__ a,
                                               const unsigned short* __restrict__ res,
                                               float* __restrict__ outp) {
  int f = threadIdx.x & 127;
  const float invN = 1.0f / (float)N_NODES;
  float m = S[f] * invN;
  float ex2 = S[128 + f] * invN;
  float af = a[f];
  float var = fmaxf(ex2 - (2.f * af - af * af) * m * m, 0.f);
  float rstd = rsqrtf(var + 1e-5f);
  float wf = w[f];
  float bvv = b[f];
  float shift = af * m;
  int rowStart = blockIdx.x * 2 + (threadIdx.x >> 7);
  for (int r = rowStart; r < N_NODES; r += gridDim.x * 2) {
    int idx = r * 128 + f;
    float v = bf2f(pre[idx]);
    float o = fmaxf(wf * (v - shift) * rstd + bvv, 0.f);
    outp[idx] = o + bf2f(res[idx]);
  }
}

extern "C" void kernel_launch(void* const* d_in, const int* in_sizes, int n_in,
                              void* d_out, int out_size, void* d_ws, size_t ws_size,
                              hipStream_t stream) {
  const float* x = (const float*)d_in[0];
  const int* ei = (const int*)d_in[1];
  const float* Wl1 = (const float*)d_in[2];
  const float* bl1 = (const float*)d_in[3];
  const float* Wr1 = (const float*)d_in[4];
  const float* Wl2 = (const float*)d_in[5];
  const float* bl2 = (const float*)d_in[6];
  const float* Wr2 = (const float*)d_in[7];
  const float* g1w = (const float*)d_in[8];
  const float* g1b = (const float*)d_in[9];
  const float* g1a = (const float*)d_in[10];
  const float* g2w = (const float*)d_in[11];
  const float* g2b = (const float*)d_in[12];
  const float* g2a = (const float*)d_in[13];
  const float* Wres = (const float*)d_in[14];
  const float* bres = (const float*)d_in[15];

  char* w = (char*)d_ws;
  const size_t FEATB = (size_t)N_NODES * D * 2;  // 12.8 MB bf16 buffer
  unsigned short* xb = (unsigned short*)(w);
  unsigned short* buf0 = (unsigned short*)(w + FEATB);
  unsigned short* agg = (unsigned short*)(w + 2 * FEATB);
  unsigned short* resb = (unsigned short*)(w + 3 * FEATB);
  char* ip = w + 4 * FEATB;
  float* stats = (float*)ip;                              // 2048 B
  int* flag = (int*)(ip + 2048);                          // 16 B
  int* cursor = (int*)(ip + 2064);                        // 512 B
  int* off = (int*)(ip + 2576);                           // 98*513*4 = 201096 B
  unsigned short* srcs = (unsigned short*)(ip + 203672);  // 98*16384*2 = 3211264 B
  unsigned short* wb = (unsigned short*)(ip + 3414936);   // 163840 B
  const size_t NEED = 4 * FEATB + 3578776;
  unsigned int* binned = (unsigned int*)agg;  // 6.4 MB alias; pre-agg use only

  float* outp = (float*)d_out;

  if (ws_size < NEED) {  // diagnostic: finite wrong answer instead of NaN
    hipMemsetAsync(d_out, 0, (size_t)out_size * 4, stream);
    return;
  }

  unsigned short* wl1b = wb;
  unsigned short* wr1b = wb + 16384;
  unsigned short* wl2b = wb + 32768;
  unsigned short* wr2b = wb + 49152;
  unsigned short* wresb = wb + 65536;

  k_detect<<<1, 256, 0, stream>>>(ei, flag, cursor, stats);
  k_castall<<<6330, 256, 0, stream>>>(x, Wl1, Wr1, Wl2, Wr2, Wres, xb, wb);

  // one-pass bucketed CSR build
  k_bin<<<NBKT, 256, 0, stream>>>(ei, flag, cursor, binned);
  k_pass2<<<NBKT, 256, 0, stream>>>(cursor, binned, off, srcs);

  const int GG = 1024;

  // layer 1
  k_agg<false><<<(N_NODES + 3) / 4, 256, 0, stream>>>(xb, off, srcs, nullptr, nullptr,
                                                      nullptr, nullptr, agg);
  k_gemm_conv<false><<<GG, 256, 0, stream>>>(agg, xb, wl1b, wr1b, bl1, buf0, stats,
                                             nullptr, nullptr, nullptr, nullptr);
  k_gemm_res<<<GG, 256, 0, stream>>>(xb, wresb, bres, resb);

  // layer 2 (norm1 fused into agg gather + conv2 B fragments)
  k_agg<true><<<(N_NODES + 3) / 4, 256, 0, stream>>>(buf0, off, srcs, stats, g1w, g1b,
                                                     g1a, agg);
  k_gemm_conv<true><<<GG, 256, 0, stream>>>(agg, buf0, wl2b, wr2b, bl2, agg, stats + 256,
                                            stats, g1w, g1b, g1a);
  k_norm2<<<1024, 256, 0, stream>>>(agg, stats + 256, g2w, g2b, g2a, resb, outp);
}

// Round 14
// 306.343 us; speedup vs baseline: 1.0719x; 1.0719x over previous
//
#include <hip/hip_runtime.h>

#define N_NODES 50000
#define N_EDGES 800000
#define D 128
#define NBKT 98       // ceil(50000/512) buckets of 512 dst nodes
#define BKT_SHIFT 9
#define BKT_CAP 16384 // padded per-bucket capacity
#define EPB 8192      // edges per binning block (98 blocks)
#define NTILES 3125   // 50000 / 16 exactly
#define GG 768        // gemm grid

typedef __attribute__((ext_vector_type(8))) short bf16x8;
typedef __attribute__((ext_vector_type(4))) float f32x4;

__device__ __forceinline__ float bf2f(unsigned short u) {
  unsigned int v = ((unsigned int)u) << 16;
  return __uint_as_float(v);
}
__device__ __forceinline__ unsigned short f2bf(float f) {
  unsigned int u = __float_as_uint(f);
  unsigned int r = (u + 0x7fffu + ((u >> 16) & 1u)) >> 16;
  return (unsigned short)r;
}

// ---- merged fp32->bf16 casts: x (6250 blocks) + 5 weights (80 blocks) ---
__global__ __launch_bounds__(256) void k_castall(const float* __restrict__ x,
                                                 const float* __restrict__ w0,
                                                 const float* __restrict__ w1,
                                                 const float* __restrict__ w2,
                                                 const float* __restrict__ w3,
                                                 const float* __restrict__ w4,
                                                 unsigned short* __restrict__ xb,
                                                 unsigned short* __restrict__ wout) {
  int b = blockIdx.x;
  const float* src;
  unsigned short* dst;
  int i;
  if (b < 6250) {
    src = x; dst = xb; i = b * 256 + threadIdx.x;
  } else {
    int b2 = b - 6250;
    int m = b2 >> 4;
    i = (b2 & 15) * 256 + threadIdx.x;
    src = (m == 0) ? w0 : (m == 1) ? w1 : (m == 2) ? w2 : (m == 3) ? w3 : w4;
    dst = wout + m * 16384;
  }
  float4 v = ((const float4*)src)[i];
  ushort4 o;
  o.x = f2bf(v.x); o.y = f2bf(v.y); o.z = f2bf(v.z); o.w = f2bf(v.w);
  ((ushort4*)dst)[i] = o;
}

// ---- edge dtype probe + cursor init + zero stats ------------------------
__global__ __launch_bounds__(256) void k_detect(const int* __restrict__ ei,
                                                int* __restrict__ flag,
                                                int* __restrict__ cursor,
                                                float* __restrict__ stats) {
  __shared__ int red[256];
  int t = threadIdx.x;
  if (t < NBKT) cursor[t] = t * BKT_CAP;
  stats[t] = 0.f;
  stats[t + 256] = 0.f;
  int acc = 0;
  for (int k = t; k < 8192; k += 256) acc |= ei[2 * k + 1];
  red[t] = acc;
  __syncthreads();
  for (int s = 128; s > 0; s >>= 1) {
    if (t < s) red[t] |= red[t + s];
    __syncthreads();
  }
  if (t == 0) flag[0] = (red[0] == 0) ? 1 : 0;  // 1 => int64
}

__device__ __forceinline__ int edge_at(const int* ei, int idx, int is64) {
  return is64 ? ei[2 * idx] : ei[idx];
}

// ---- one-pass binning into padded buckets -------------------------------
__global__ __launch_bounds__(256) void k_bin(const int* __restrict__ ei,
                                             const int* __restrict__ flag,
                                             int* __restrict__ cursor,
                                             unsigned int* __restrict__ binned) {
  __shared__ int h[128];
  __shared__ int resv[128];
  int t = threadIdx.x;
  if (t < 128) h[t] = 0;
  __syncthreads();
  int is64 = flag[0];
  int start = blockIdx.x * EPB;
  int end = min(start + EPB, N_EDGES);
  for (int e = start + t; e < end; e += 256) {
    int d = edge_at(ei, N_EDGES + e, is64);
    if ((unsigned)d < N_NODES) atomicAdd(&h[d >> BKT_SHIFT], 1);
  }
  __syncthreads();
  if (t < NBKT) {
    resv[t] = h[t] ? atomicAdd(&cursor[t], h[t]) : 0;
    h[t] = 0;
  }
  __syncthreads();
  for (int e = start + t; e < end; e += 256) {
    int d = edge_at(ei, N_EDGES + e, is64);
    int sv = edge_at(ei, e, is64);
    if ((unsigned)d < N_NODES && (unsigned)sv < N_NODES) {
      int b = d >> BKT_SHIFT;
      int r = atomicAdd(&h[b], 1);
      int pos = resv[b] + r;
      if (pos < (b + 1) * BKT_CAP) binned[pos] = (unsigned)sv | ((unsigned)d << 16);
    }
  }
}

// ---- per-bucket CSR: off (bucket-padded, stride 513) + srcs scatter -----
__global__ __launch_bounds__(256) void k_pass2(const int* __restrict__ cursor,
                                               const unsigned int* __restrict__ binned,
                                               int* __restrict__ off,
                                               unsigned short* __restrict__ srcs) {
  __shared__ int h[512];
  __shared__ int ps[256];
  __shared__ int sc[512];
  int t = threadIdx.x;
  int b = blockIdx.x;
  int base = b * BKT_CAP;
  int cnt = min(cursor[b] - base, BKT_CAP);
  h[t] = 0; h[t + 256] = 0;
  __syncthreads();
  for (int e = base + t; e < base + cnt; e += 256) {
    unsigned v = binned[e];
    int l = (int)(v >> 16) - (b << BKT_SHIFT);
    atomicAdd(&h[l], 1);
  }
  __syncthreads();
  int pair = h[2 * t] + h[2 * t + 1];
  ps[t] = pair;
  __syncthreads();
  for (int s = 1; s < 256; s <<= 1) {
    int add = (t >= s) ? ps[t - s] : 0;
    __syncthreads();
    ps[t] += add;
    __syncthreads();
  }
  int pexcl = ps[t] - pair;
  sc[2 * t] = pexcl;
  sc[2 * t + 1] = pexcl + h[2 * t];
  __syncthreads();
  h[t] = 0; h[t + 256] = 0;
  off[b * 513 + t] = base + sc[t];
  off[b * 513 + t + 256] = base + sc[t + 256];
  if (t == 0) off[b * 513 + 512] = base + cnt;
  __syncthreads();
  for (int e = base + t; e < base + cnt; e += 256) {
    unsigned v = binned[e];
    int l = (int)(v >> 16) - (b << BKT_SHIFT);
    int r = atomicAdd(&h[l], 1);
    srcs[base + sc[l] + r] = (unsigned short)(v & 0xffffu);
  }
}

// ---- mean aggregation, 2x-unrolled gather -------------------------------
template <bool NORM>
__device__ __forceinline__ void accum8(float* a, uint4 v, const float* sc,
                                       const float* bt) {
  const unsigned int* pv = (const unsigned int*)&v;
#pragma unroll
  for (int h = 0; h < 4; ++h) {
    float lo = bf2f((unsigned short)(pv[h] & 0xffffu));
    float hi = bf2f((unsigned short)(pv[h] >> 16));
    if (NORM) {
      a[2 * h] += fmaxf(fmaf(sc[2 * h], lo, bt[2 * h]), 0.f);
      a[2 * h + 1] += fmaxf(fmaf(sc[2 * h + 1], hi, bt[2 * h + 1]), 0.f);
    } else {
      a[2 * h] += lo;
      a[2 * h + 1] += hi;
    }
  }
}

template <bool NORM>
__global__ __launch_bounds__(256) void k_agg(const unsigned short* __restrict__ feat,
                                             const int* __restrict__ off,
                                             const unsigned short* __restrict__ srcs,
                                             const float* __restrict__ Sin,
                                             const float* __restrict__ gw,
                                             const float* __restrict__ gb,
                                             const float* __restrict__ ga,
                                             unsigned short* __restrict__ agg) {
  int wv = threadIdx.x >> 6;
  int lane = threadIdx.x & 63;
  int node = blockIdx.x * 4 + wv;
  if (node >= N_NODES) return;
  int q = lane >> 4, s = lane & 15;

  float sc[8], bt[8];
  if (NORM) {
    const float invN = 1.0f / (float)N_NODES;
#pragma unroll
    for (int i = 0; i < 8; ++i) {
      int f = s * 8 + i;
      float m = Sin[f] * invN;
      float ex2 = Sin[128 + f] * invN;
      float af = ga[f];
      float var = fmaxf(ex2 - (2.f * af - af * af) * m * m, 0.f);
      float rstd = rsqrtf(var + 1e-5f);
      sc[i] = gw[f] * rstd;
      bt[i] = gb[f] - sc[i] * af * m;
    }
  }

  int oidx = (node >> BKT_SHIFT) * 513 + (node & 511);
  int b = off[oidx], e = off[oidx + 1];
  const uint4* fp = (const uint4*)feat;
  float a[8] = {0.f, 0.f, 0.f, 0.f, 0.f, 0.f, 0.f, 0.f};
  for (int cb = b; cb < e; cb += 64) {
    int n = min(64, e - cb);
    int jv = (lane < n) ? (int)srcs[cb + lane] : 0;
    int kmax = (n + 3) >> 2;
    int k = 0;
    for (; k + 2 <= kmax; k += 2) {
      int t0 = 4 * k + q;
      int t1 = t0 + 4;
      int j0 = __shfl(jv, t0);
      int j1 = __shfl(jv, t1);
      uint4 v0 = fp[j0 * 16 + s];
      uint4 v1 = fp[j1 * 16 + s];
      if (t0 < n) accum8<NORM>(a, v0, sc, bt);
      if (t1 < n) accum8<NORM>(a, v1, sc, bt);
    }
    if (k < kmax) {
      int t0 = 4 * k + q;
      int j0 = __shfl(jv, t0);
      uint4 v0 = fp[j0 * 16 + s];
      if (t0 < n) accum8<NORM>(a, v0, sc, bt);
    }
  }
#pragma unroll
  for (int i = 0; i < 8; ++i) {
    a[i] += __shfl_xor(a[i], 16);
    a[i] += __shfl_xor(a[i], 32);
  }
  if (q == 0) {
    float inv = 1.0f / (float)max(e - b, 1);
    uint4 o;
    o.x = (unsigned)f2bf(a[0] * inv) | ((unsigned)f2bf(a[1] * inv) << 16);
    o.y = (unsigned)f2bf(a[2] * inv) | ((unsigned)f2bf(a[3] * inv) << 16);
    o.z = (unsigned)f2bf(a[4] * inv) | ((unsigned)f2bf(a[5] * inv) << 16);
    o.w = (unsigned)f2bf(a[6] * inv) | ((unsigned)f2bf(a[7] * inv) << 16);
    ((uint4*)agg)[node * 16 + s] = o;
  }
}

// ---- weight-stationary fused GEMM, 2-tile unrolled, atomic stats --------
// out = A@W1^T + B@W2^T + bias (+stats); FUSERES: outres = B@Wres^T + bres;
// NORMB: GraphNorm+ReLU on B fragments via LDS params.
// NOTE: all pointer args are genuinely non-aliased at every call site.
template <bool FUSERES, bool NORMB>
__global__ __launch_bounds__(256) void k_gemm(const unsigned short* __restrict__ A,
                                              const unsigned short* __restrict__ B,
                                              const unsigned short* __restrict__ W1,
                                              const unsigned short* __restrict__ W2,
                                              const unsigned short* __restrict__ Wres,
                                              const float* __restrict__ bias,
                                              const float* __restrict__ bres,
                                              unsigned short* __restrict__ outv,
                                              unsigned short* __restrict__ outres,
                                              float* __restrict__ S,
                                              const float* __restrict__ Sin,
                                              const float* __restrict__ gw,
                                              const float* __restrict__ gb,
                                              const float* __restrict__ ga) {
  __shared__ float sred[2][128];
  __shared__ float nsc[128], nbt[128];
  const int tid = threadIdx.x;
  const int lane = tid & 63;
  const int wv = tid >> 6;
  const int quad = lane >> 4;
  const int l16 = lane & 15;
  const int colBase = wv * 32;

  if (NORMB) {
    if (tid < 128) {
      const float invN = 1.0f / (float)N_NODES;
      float m = Sin[tid] * invN;
      float ex2 = Sin[128 + tid] * invN;
      float af = ga[tid];
      float var = fmaxf(ex2 - (2.f * af - af * af) * m * m, 0.f);
      float rstd = rsqrtf(var + 1e-5f);
      float scv = gw[tid] * rstd;
      nsc[tid] = scv;
      nbt[tid] = gb[tid] - scv * af * m;
    }
    __syncthreads();
  }

  bf16x8 w1f[2][4], w2f[2][4], wrf[2][4];
  float bv[2], bvR[2];
#pragma unroll
  for (int c2 = 0; c2 < 2; ++c2) {
    int col = colBase + c2 * 16 + l16;
    bv[c2] = bias[col];
    if (FUSERES) bvR[c2] = bres[col];
#pragma unroll
    for (int ks = 0; ks < 4; ++ks) {
      w1f[c2][ks] = *((const bf16x8*)&W1[col * 128 + ks * 32 + quad * 8]);
      w2f[c2][ks] = *((const bf16x8*)&W2[col * 128 + ks * 32 + quad * 8]);
      if (FUSERES) wrf[c2][ks] = *((const bf16x8*)&Wres[col * 128 + ks * 32 + quad * 8]);
    }
  }

  float p1[2] = {0.f, 0.f}, p2[2] = {0.f, 0.f};

  for (int t0 = 2 * blockIdx.x; t0 < NTILES - 1; t0 += 2 * gridDim.x) {
    bf16x8 af[2][4], bfr[2][4];
#pragma unroll
    for (int u = 0; u < 2; ++u) {
      int arow = (t0 + u) * 16 + l16;
#pragma unroll
      for (int ks = 0; ks < 4; ++ks) {
        af[u][ks] = *((const bf16x8*)&A[arow * 128 + ks * 32 + quad * 8]);
        bfr[u][ks] = *((const bf16x8*)&B[arow * 128 + ks * 32 + quad * 8]);
      }
    }
    if (NORMB) {
#pragma unroll
      for (int u = 0; u < 2; ++u)
#pragma unroll
        for (int ks = 0; ks < 4; ++ks) {
          int f0 = ks * 32 + quad * 8;
#pragma unroll
          for (int j = 0; j < 8; ++j) {
            float xv = bf2f((unsigned short)bfr[u][ks][j]);
            bfr[u][ks][j] = (short)f2bf(fmaxf(fmaf(nsc[f0 + j], xv, nbt[f0 + j]), 0.f));
          }
        }
    }
    f32x4 acc[2][2], accR[2][2];
#pragma unroll
    for (int u = 0; u < 2; ++u)
#pragma unroll
      for (int c2 = 0; c2 < 2; ++c2) {
        acc[u][c2] = (f32x4){0.f, 0.f, 0.f, 0.f};
        if (FUSERES) accR[u][c2] = (f32x4){0.f, 0.f, 0.f, 0.f};
      }
#pragma unroll
    for (int u = 0; u < 2; ++u)
#pragma unroll
      for (int c2 = 0; c2 < 2; ++c2)
#pragma unroll
        for (int ks = 0; ks < 4; ++ks) {
          acc[u][c2] = __builtin_amdgcn_mfma_f32_16x16x32_bf16(af[u][ks], w1f[c2][ks], acc[u][c2], 0, 0, 0);
          acc[u][c2] = __builtin_amdgcn_mfma_f32_16x16x32_bf16(bfr[u][ks], w2f[c2][ks], acc[u][c2], 0, 0, 0);
          if (FUSERES)
            accR[u][c2] = __builtin_amdgcn_mfma_f32_16x16x32_bf16(bfr[u][ks], wrf[c2][ks], accR[u][c2], 0, 0, 0);
        }
#pragma unroll
    for (int u = 0; u < 2; ++u)
#pragma unroll
      for (int c2 = 0; c2 < 2; ++c2) {
        int col = colBase + c2 * 16 + l16;
#pragma unroll
        for (int g = 0; g < 4; ++g) {
          int row = (t0 + u) * 16 + quad * 4 + g;
          float v = acc[u][c2][g] + bv[c2];
          outv[row * 128 + col] = f2bf(v);
          p1[c2] += v;
          p2[c2] += v * v;
          if (FUSERES) outres[row * 128 + col] = f2bf(accR[u][c2][g] + bvR[c2]);
        }
      }
  }

  if (blockIdx.x == gridDim.x - 1) {  // tail tile 3124
    const int tile = NTILES - 1;
    int arow = tile * 16 + l16;
    bf16x8 af[4], bfr[4];
#pragma unroll
    for (int ks = 0; ks < 4; ++ks) {
      af[ks] = *((const bf16x8*)&A[arow * 128 + ks * 32 + quad * 8]);
      bfr[ks] = *((const bf16x8*)&B[arow * 128 + ks * 32 + quad * 8]);
    }
    if (NORMB) {
#pragma unroll
      for (int ks = 0; ks < 4; ++ks) {
        int f0 = ks * 32 + quad * 8;
#pragma unroll
        for (int j = 0; j < 8; ++j) {
          float xv = bf2f((unsigned short)bfr[ks][j]);
          bfr[ks][j] = (short)f2bf(fmaxf(fmaf(nsc[f0 + j], xv, nbt[f0 + j]), 0.f));
        }
      }
    }
    f32x4 acc[2], accR[2];
#pragma unroll
    for (int c2 = 0; c2 < 2; ++c2) {
      acc[c2] = (f32x4){0.f, 0.f, 0.f, 0.f};
      if (FUSERES) accR[c2] = (f32x4){0.f, 0.f, 0.f, 0.f};
    }
#pragma unroll
    for (int c2 = 0; c2 < 2; ++c2)
#pragma unroll
      for (int ks = 0; ks < 4; ++ks) {
        acc[c2] = __builtin_amdgcn_mfma_f32_16x16x32_bf16(af[ks], w1f[c2][ks], acc[c2], 0, 0, 0);
        acc[c2] = __builtin_amdgcn_mfma_f32_16x16x32_bf16(bfr[ks], w2f[c2][ks], acc[c2], 0, 0, 0);
        if (FUSERES)
          accR[c2] = __builtin_amdgcn_mfma_f32_16x16x32_bf16(bfr[ks], wrf[c2][ks], accR[c2], 0, 0, 0);
      }
#pragma unroll
    for (int c2 = 0; c2 < 2; ++c2) {
      int col = colBase + c2 * 16 + l16;
#pragma unroll
      for (int g = 0; g < 4; ++g) {
        int row = tile * 16 + quad * 4 + g;
        float v = acc[c2][g] + bv[c2];
        outv[row * 128 + col] = f2bf(v);
        p1[c2] += v;
        p2[c2] += v * v;
        if (FUSERES) outres[row * 128 + col] = f2bf(accR[c2][g] + bvR[c2]);
      }
    }
  }

#pragma unroll
  for (int c2 = 0; c2 < 2; ++c2) {
    p1[c2] += __shfl_xor(p1[c2], 16); p1[c2] += __shfl_xor(p1[c2], 32);
    p2[c2] += __shfl_xor(p2[c2], 16); p2[c2] += __shfl_xor(p2[c2], 32);
  }
  if (quad == 0) {
#pragma unroll
    for (int c2 = 0; c2 < 2; ++c2) {
      sred[0][colBase + c2 * 16 + l16] = p1[c2];
      sred[1][colBase + c2 * 16 + l16] = p2[c2];
    }
  }
  __syncthreads();
  if (tid < 128) atomicAdd(&S[tid], sred[0][tid]);
  else atomicAdd(&S[tid], sred[1][tid - 128]);
}

// ---- final GraphNorm + ReLU + bf16 residual -> fp32 d_out ---------------
__global__ __launch_bounds__(256) void k_norm2(const unsigned short* __restrict__ pre,
                                               const float* __restrict__ S,
                                               const float* __restrict__ w,
                                               const float* __restrict__ b,
                                               const float* __restrict__ a,
                                               const unsigned short* __restrict__ res,
                                               float* __restrict__ outp) {
  int f = threadIdx.x & 127;
  const float invN = 1.0f / (float)N_NODES;
  float m = S[f] * invN;
  float ex2 = S[128 + f] * invN;
  float af = a[f];
  float var = fmaxf(ex2 - (2.f * af - af * af) * m * m, 0.f);
  float rstd = rsqrtf(var + 1e-5f);
  float wf = w[f];
  float bvv = b[f];
  float shift = af * m;
  int rowStart = blockIdx.x * 2 + (threadIdx.x >> 7);
  for (int r = rowStart; r < N_NODES; r += gridDim.x * 2) {
    int idx = r * 128 + f;
    float v = bf2f(pre[idx]);
    float o = fmaxf(wf * (v - shift) * rstd + bvv, 0.f);
    outp[idx] = o + bf2f(res[idx]);
  }
}

extern "C" void kernel_launch(void* const* d_in, const int* in_sizes, int n_in,
                              void* d_out, int out_size, void* d_ws, size_t ws_size,
                              hipStream_t stream) {
  const float* x = (const float*)d_in[0];
  const int* ei = (const int*)d_in[1];
  const float* Wl1 = (const float*)d_in[2];
  const float* bl1 = (const float*)d_in[3];
  const float* Wr1 = (const float*)d_in[4];
  const float* Wl2 = (const float*)d_in[5];
  const float* bl2 = (const float*)d_in[6];
  const float* Wr2 = (const float*)d_in[7];
  const float* g1w = (const float*)d_in[8];
  const float* g1b = (const float*)d_in[9];
  const float* g1a = (const float*)d_in[10];
  const float* g2w = (const float*)d_in[11];
  const float* g2b = (const float*)d_in[12];
  const float* g2a = (const float*)d_in[13];
  const float* Wres = (const float*)d_in[14];
  const float* bres = (const float*)d_in[15];

  char* w = (char*)d_ws;
  const size_t FEATB = (size_t)N_NODES * D * 2;  // 12.8 MB bf16 buffer
  unsigned short* xb = (unsigned short*)(w);      // x bf16; reused as gemm2 out
  unsigned short* buf0 = (unsigned short*)(w + FEATB);
  unsigned short* agg = (unsigned short*)(w + 2 * FEATB);
  unsigned short* resb = (unsigned short*)(w + 3 * FEATB);
  char* ip = w + 4 * FEATB;
  float* stats = (float*)ip;                              // 2048 B
  int* flag = (int*)(ip + 2048);                          // 16 B
  int* cursor = (int*)(ip + 2064);                        // 512 B
  int* off = (int*)(ip + 2576);                           // 98*513*4 = 201096 B
  unsigned short* srcs = (unsigned short*)(ip + 203672);  // 3211264 B
  unsigned short* wb = (unsigned short*)(ip + 3414936);   // 163840 B
  const size_t NEED = 4 * FEATB + 3578776;
  unsigned int* binned = (unsigned int*)agg;  // alias; pre-agg use only

  float* outp = (float*)d_out;

  if (ws_size < NEED) {  // diagnostic: finite wrong answer instead of NaN
    hipMemsetAsync(d_out, 0, (size_t)out_size * 4, stream);
    return;
  }

  unsigned short* wl1b = wb;
  unsigned short* wr1b = wb + 16384;
  unsigned short* wl2b = wb + 32768;
  unsigned short* wr2b = wb + 49152;
  unsigned short* wresb = wb + 65536;

  k_detect<<<1, 256, 0, stream>>>(ei, flag, cursor, stats);
  k_castall<<<6330, 256, 0, stream>>>(x, Wl1, Wr1, Wl2, Wr2, Wres, xb, wb);

  // one-pass bucketed CSR build
  k_bin<<<NBKT, 256, 0, stream>>>(ei, flag, cursor, binned);
  k_pass2<<<NBKT, 256, 0, stream>>>(cursor, binned, off, srcs);

  // layer 1: fused [conv GEMM + stats | residual GEMM] — no aliasing
  k_agg<false><<<(N_NODES + 3) / 4, 256, 0, stream>>>(xb, off, srcs, nullptr, nullptr,
                                                      nullptr, nullptr, agg);
  k_gemm<true, false><<<GG, 256, 0, stream>>>(agg, xb, wl1b, wr1b, wresb, bl1, bres,
                                              buf0, resb, stats,
                                              nullptr, nullptr, nullptr, nullptr);

  // layer 2: xb is dead after gemm1 -> gemm2 writes xb (A=agg, B=buf0 distinct)
  k_agg<true><<<(N_NODES + 3) / 4, 256, 0, stream>>>(buf0, off, srcs, stats, g1w, g1b,
                                                     g1a, agg);
  k_gemm<false, true><<<GG, 256, 0, stream>>>(agg, buf0, wl2b, wr2b, nullptr, bl2,
                                              nullptr, xb, nullptr, stats + 256,
                                              stats, g1w, g1b, g1a);
  k_norm2<<<1024, 256, 0, stream>>>(xb, stats + 256, g2w, g2b, g2a, resb, outp);
}